// Round 3
// baseline (226.541 us; speedup 1.0000x reference)
//
#include <hip/hip_runtime.h>

#define OUT 7
#define NCH 256
#define NB 2
#define NPER 256
#define NROI (NB * NPER)
#define TPR (NCH * OUT * OUT)   // 12544 outputs per RoI

// Channels-last bf16 pyramid layout in d_ws (elements, not bytes):
//   level l: base BASEl, shape [B, P_l, 256], elem ((b*P + p)*256 + c)
#define P0 (200 * 200)
#define P1 (100 * 100)
#define P2 (50 * 50)
#define P3 (25 * 25)
#define BASE0 0
#define BASE1 (BASE0 + NB * P0 * NCH)   // 20,480,000
#define BASE2 (BASE1 + NB * P1 * NCH)   // 25,600,000
#define BASE3 (BASE2 + NB * P2 * NCH)   // 26,880,000
#define WS_ELEMS (BASE3 + NB * P3 * NCH) // 27,200,000 (54.4 MB as ushort)

__device__ __forceinline__ float rfl_f(float v) {
    return __int_as_float(__builtin_amdgcn_readfirstlane(__float_as_int(v)));
}

__device__ __forceinline__ unsigned short f2bf_rne(float f) {
    unsigned int u = __float_as_uint(f);
    u += 0x7FFFu + ((u >> 16) & 1u);   // round-to-nearest-even
    return (unsigned short)(u >> 16);
}

__device__ __forceinline__ float bf2f(unsigned short h) {
    return __uint_as_float((unsigned int)h << 16);
}

// ---- transpose [B,256,P] fp32 -> [B,P,256] bf16, 64x64 LDS tiles ----
__global__ __launch_bounds__(256) void transpose_cl_kernel(
        const float* __restrict__ src, unsigned short* __restrict__ dst, int P) {
    __shared__ float tile[64][65];
    int p0 = blockIdx.x * 64;
    int c0 = blockIdx.y * 64;
    int b  = blockIdx.z;
    int tx = threadIdx.x & 63;   // p_local on read, c_local on write
    int ty = threadIdx.x >> 6;   // 0..3

#pragma unroll
    for (int k = 0; k < 16; ++k) {
        int cc = ty + 4 * k;          // 0..63
        int p  = p0 + tx;
        float v = (p < P) ? src[((size_t)(b * NCH + c0 + cc)) * P + p] : 0.0f;
        tile[cc][tx] = v;
    }
    __syncthreads();
#pragma unroll
    for (int k = 0; k < 16; ++k) {
        int pp = ty + 4 * k;          // 0..63
        int p  = p0 + pp;
        if (p < P)
            dst[((size_t)b * P + p) * NCH + c0 + tx] = f2bf_rne(tile[tx][pp]);
    }
}

// ---- main: block = (roi, 64-channel chunk); lanes = channels (coalesced) ----
__global__ __launch_bounds__(256) void roi_align_cl_kernel(
        const unsigned short* __restrict__ t,
        const float* __restrict__ boxes, float* __restrict__ out) {
    __shared__ float lds[64 * 49];
    int blk  = blockIdx.x;
    int r    = blk >> 2;
    int q    = blk & 3;               // channel chunk
    int lane = threadIdx.x & 63;
    int wave = threadIdx.x >> 6;

    // ---- wave-uniform RoI meta ----
    float bx1 = rfl_f(boxes[r * 4 + 0]);
    float by1 = rfl_f(boxes[r * 4 + 1]);
    float bx2 = rfl_f(boxes[r * 4 + 2]);
    float by2 = rfl_f(boxes[r * 4 + 3]);

    float area = (bx2 - bx1) * (by2 - by1);
    float s    = sqrtf(area);
    float lvl  = floorf(4.0f + log2f(s * (1.0f / 224.0f) + 1e-6f));
    lvl        = fminf(fmaxf(lvl, 2.0f), 5.0f);
    int level  = __builtin_amdgcn_readfirstlane((int)lvl - 2);

    int H; float scale; size_t base;
    switch (level) {
        case 0:  H = 200; scale = 0.25f;    base = BASE0; break;
        case 1:  H = 100; scale = 0.125f;   base = BASE1; break;
        case 2:  H = 50;  scale = 0.0625f;  base = BASE2; break;
        default: H = 25;  scale = 0.03125f; base = BASE3; break;
    }
    float Hf = (float)H;

    float x1 = bx1 * scale;
    float y1 = by1 * scale;
    float roi_w = fmaxf(bx2 * scale - x1, 1.0f);
    float roi_h = fmaxf(by2 * scale - y1, 1.0f);
    float bin_w = roi_w * (1.0f / OUT);
    float bin_h = roi_h * (1.0f / OUT);

    int bidx = r >> 8;  // NPER == 256
    const unsigned short* plane =
        t + base + (size_t)bidx * (size_t)(H * H) * NCH + (size_t)(q * 64 + lane);

    // waves split the 49 pixels
    for (int p = wave; p < OUT * OUT; p += 4) {
        int ph = p / OUT;
        int pw = p - ph * OUT;

        float wgt[16];
        int   off[16];
#pragma unroll
        for (int iy = 0; iy < 2; ++iy) {
            float y   = y1 + ((float)ph + (iy ? 0.75f : 0.25f)) * bin_h;
            bool  oky = (y >= -1.0f) && (y <= Hf);
            y = fmaxf(y, 0.0f);
            int yl = (int)y;
            int yh;
            if (yl >= H - 1) { yl = H - 1; yh = H - 1; y = (float)yl; }
            else             { yh = yl + 1; }
            float ly = y - (float)yl;
            float hy = 1.0f - ly;
            int rl = yl * H;
            int rh = yh * H;
#pragma unroll
            for (int ix = 0; ix < 2; ++ix) {
                float x  = x1 + ((float)pw + (ix ? 0.75f : 0.25f)) * bin_w;
                bool  ok = oky && (x >= -1.0f) && (x <= Hf);
                x = fmaxf(x, 0.0f);
                int xl = (int)x;
                int xh;
                if (xl >= H - 1) { xl = H - 1; xh = H - 1; x = (float)xl; }
                else             { xh = xl + 1; }
                float lx = x - (float)xl;
                float hx = 1.0f - lx;
                float m  = ok ? 0.25f : 0.0f;
                int k = (iy * 2 + ix) * 4;
                wgt[k + 0] = hy * hx * m;  off[k + 0] = (rl + xl) * NCH;
                wgt[k + 1] = hy * lx * m;  off[k + 1] = (rl + xh) * NCH;
                wgt[k + 2] = ly * hx * m;  off[k + 2] = (rh + xl) * NCH;
                wgt[k + 3] = ly * lx * m;  off[k + 3] = (rh + xh) * NCH;
            }
        }

        unsigned short v[16];
#pragma unroll
        for (int k = 0; k < 16; ++k) v[k] = plane[off[k]];

        float acc = 0.0f;
#pragma unroll
        for (int k = 0; k < 16; ++k) acc = fmaf(wgt[k], bf2f(v[k]), acc);

        lds[lane * 49 + p] = acc;
    }
    __syncthreads();

    // coalesced write: out[r][q*64 + c_l][ph][pw] -> contiguous 3136 floats
    float* dst = out + (size_t)r * TPR + (size_t)q * 3136;
    for (int e = threadIdx.x; e < 3136; e += 256) {
        int c_l = e / 49;
        int p   = e - c_l * 49;
        dst[e] = lds[c_l * 49 + p];
    }
}

// ================= fallback (R2 kernel, used when ws too small) =============
__global__ __launch_bounds__(256) void roi_align_direct_kernel(
        const float* __restrict__ f0, const float* __restrict__ f1,
        const float* __restrict__ f2, const float* __restrict__ f3,
        const float* __restrict__ boxes, float* __restrict__ out) {
    int b    = blockIdx.x;
    int xcd  = b & 7;
    int slot = b >> 3;
    int rr   = slot / 49;
    int j    = slot - rr * 49;
    int r    = (rr << 3) | xcd;

    int lin = j * 256 + (int)threadIdx.x;
    int pw  = lin % OUT;
    int t   = lin / OUT;
    int ph  = t % OUT;
    int c   = t / OUT;

    float bx1 = rfl_f(boxes[r * 4 + 0]);
    float by1 = rfl_f(boxes[r * 4 + 1]);
    float bx2 = rfl_f(boxes[r * 4 + 2]);
    float by2 = rfl_f(boxes[r * 4 + 3]);

    float area = (bx2 - bx1) * (by2 - by1);
    float s    = sqrtf(area);
    float lvl  = floorf(4.0f + log2f(s * (1.0f / 224.0f) + 1e-6f));
    lvl        = fminf(fmaxf(lvl, 2.0f), 5.0f);
    int level  = __builtin_amdgcn_readfirstlane((int)lvl - 2);

    const float* f;
    int H;
    float scale;
    switch (level) {
        case 0:  f = f0; H = 200; scale = 0.25f;    break;
        case 1:  f = f1; H = 100; scale = 0.125f;   break;
        case 2:  f = f2; H = 50;  scale = 0.0625f;  break;
        default: f = f3; H = 25;  scale = 0.03125f; break;
    }
    float Hf = (float)H;

    float x1 = bx1 * scale;
    float y1 = by1 * scale;
    float roi_w = fmaxf(bx2 * scale - x1, 1.0f);
    float roi_h = fmaxf(by2 * scale - y1, 1.0f);
    float bin_w = roi_w * (1.0f / OUT);
    float bin_h = roi_h * (1.0f / OUT);

    int bidx = r >> 8;
    const float* plane = f + (size_t)(bidx * NCH + c) * (size_t)(H * H);

    float wgt[16];
    int   off[16];
#pragma unroll
    for (int iy = 0; iy < 2; ++iy) {
        float y   = y1 + ((float)ph + (iy ? 0.75f : 0.25f)) * bin_h;
        bool  oky = (y >= -1.0f) && (y <= Hf);
        y = fmaxf(y, 0.0f);
        int yl = (int)y;
        int yh;
        if (yl >= H - 1) { yl = H - 1; yh = H - 1; y = (float)yl; }
        else             { yh = yl + 1; }
        float ly = y - (float)yl;
        float hy = 1.0f - ly;
        int rl = yl * H;
        int rh = yh * H;
#pragma unroll
        for (int ix = 0; ix < 2; ++ix) {
            float x  = x1 + ((float)pw + (ix ? 0.75f : 0.25f)) * bin_w;
            bool  ok = oky && (x >= -1.0f) && (x <= Hf);
            x = fmaxf(x, 0.0f);
            int xl = (int)x;
            int xh;
            if (xl >= H - 1) { xl = H - 1; xh = H - 1; x = (float)xl; }
            else             { xh = xl + 1; }
            float lx = x - (float)xl;
            float hx = 1.0f - lx;
            float m  = ok ? 0.25f : 0.0f;
            int k = (iy * 2 + ix) * 4;
            wgt[k + 0] = hy * hx * m;  off[k + 0] = rl + xl;
            wgt[k + 1] = hy * lx * m;  off[k + 1] = rl + xh;
            wgt[k + 2] = ly * hx * m;  off[k + 2] = rh + xl;
            wgt[k + 3] = ly * lx * m;  off[k + 3] = rh + xh;
        }
    }

    float v[16];
#pragma unroll
    for (int k = 0; k < 16; ++k) v[k] = plane[off[k]];

    float acc = 0.0f;
#pragma unroll
    for (int k = 0; k < 16; ++k) acc = fmaf(wgt[k], v[k], acc);

    out[(size_t)r * TPR + lin] = acc;
}

extern "C" void kernel_launch(void* const* d_in, const int* in_sizes, int n_in,
                              void* d_out, int out_size, void* d_ws, size_t ws_size,
                              hipStream_t stream) {
    const float* f0    = (const float*)d_in[0];
    const float* f1    = (const float*)d_in[1];
    const float* f2    = (const float*)d_in[2];
    const float* f3    = (const float*)d_in[3];
    const float* boxes = (const float*)d_in[4];
    float* out         = (float*)d_out;

    if (ws_size >= (size_t)WS_ELEMS * sizeof(unsigned short)) {
        unsigned short* t = (unsigned short*)d_ws;
        // transpose each pyramid level to channels-last bf16
        transpose_cl_kernel<<<dim3((P0 + 63) / 64, 4, NB), 256, 0, stream>>>(f0, t + BASE0, P0);
        transpose_cl_kernel<<<dim3((P1 + 63) / 64, 4, NB), 256, 0, stream>>>(f1, t + BASE1, P1);
        transpose_cl_kernel<<<dim3((P2 + 63) / 64, 4, NB), 256, 0, stream>>>(f2, t + BASE2, P2);
        transpose_cl_kernel<<<dim3((P3 + 63) / 64, 4, NB), 256, 0, stream>>>(f3, t + BASE3, P3);
        roi_align_cl_kernel<<<NROI * 4, 256, 0, stream>>>(t, boxes, out);
    } else {
        roi_align_direct_kernel<<<NROI * 49, 256, 0, stream>>>(f0, f1, f2, f3, boxes, out);
    }
}